// Round 6
// baseline (358.900 us; speedup 1.0000x reference)
//
#include <hip/hip_runtime.h>

#define FEAT 128

typedef __attribute__((ext_vector_type(8))) _Float16 f16x8;
typedef __attribute__((ext_vector_type(2))) _Float16 f16x2;
typedef __attribute__((ext_vector_type(4))) float f32x4;

static __device__ __forceinline__ int wave_incl_scan(int v, int lane) {
#pragma unroll
    for (int off = 1; off < 64; off <<= 1) {
        int u = __shfl_up(v, off, 64);
        if (lane >= off) v += u;
    }
    return v;
}

// ---------------------------------------------------------------------------
// CSR build: histogram -> 3-phase parallel scan -> scatter.
// ---------------------------------------------------------------------------

__global__ void hist_kernel(const int* __restrict__ dst, int* __restrict__ deg, int E) {
    int e = blockIdx.x * blockDim.x + threadIdx.x;
    if (e < E) atomicAdd(&deg[dst[e]], 1);
}

__global__ __launch_bounds__(1024) void scan1_kernel(const int* __restrict__ deg,
                                                     int* __restrict__ row_ptr,
                                                     int* __restrict__ bsum, int N) {
    int i = blockIdx.x * 1024 + threadIdx.x;
    int lane = threadIdx.x & 63;
    int w = threadIdx.x >> 6;
    int v = (i < N) ? deg[i] : 0;
    int inc = wave_incl_scan(v, lane);
    __shared__ int wsum[16];
    if (lane == 63) wsum[w] = inc;
    __syncthreads();
    if (w == 0) {
        int s = (lane < 16) ? wsum[lane] : 0;
        int si = wave_incl_scan(s, lane);
        if (lane < 16) wsum[lane] = si - s;
    }
    __syncthreads();
    int exc = inc - v + wsum[w];
    if (i < N) row_ptr[i] = exc;
    if (threadIdx.x == 1023) bsum[blockIdx.x] = exc + v;
}

__global__ __launch_bounds__(1024) void scan2_kernel(const int* __restrict__ bsum,
                                                     int* __restrict__ boff,
                                                     int* __restrict__ row_ptr,
                                                     int nb, int N, int E) {
    int tid = threadIdx.x;
    int lane = tid & 63;
    int w = tid >> 6;
    int v = (tid < nb) ? bsum[tid] : 0;
    int inc = wave_incl_scan(v, lane);
    __shared__ int wsum[16];
    if (lane == 63) wsum[w] = inc;
    __syncthreads();
    if (w == 0) {
        int s = (lane < 16) ? wsum[lane] : 0;
        int si = wave_incl_scan(s, lane);
        if (lane < 16) wsum[lane] = si - s;
    }
    __syncthreads();
    if (tid < nb) boff[tid] = inc - v + wsum[w];
    if (tid == 0) row_ptr[N] = E;
}

__global__ void scan3_kernel(int* __restrict__ row_ptr, const int* __restrict__ boff, int N) {
    int i = blockIdx.x * blockDim.x + threadIdx.x;
    if (i < N) row_ptr[i] += boff[i >> 10];
}

__global__ void scatter_kernel(const int* __restrict__ src, const int* __restrict__ dst,
                               const int* __restrict__ row_ptr, int* __restrict__ fill,
                               int* __restrict__ esrc, int E) {
    int e = blockIdx.x * blockDim.x + threadIdx.x;
    if (e < E) {
        int d = dst[e];
        int pos = row_ptr[d] + atomicAdd(&fill[d], 1);
        esrc[pos] = src[e];
    }
}

// ---------------------------------------------------------------------------
// fp32 -> fp16 converts (weights once, feats once).
// ---------------------------------------------------------------------------

__global__ void wcvt_kernel(const float* __restrict__ tw, const float* __restrict__ pw,
                            _Float16* __restrict__ wt, _Float16* __restrict__ wp, int n) {
    int i = blockIdx.x * blockDim.x + threadIdx.x;
    if (i < n) { wt[i] = (_Float16)tw[i]; wp[i] = (_Float16)pw[i]; }
}

__global__ void xcvt_kernel(const float* __restrict__ x, _Float16* __restrict__ x16, int n4) {
    int i = blockIdx.x * blockDim.x + threadIdx.x;
    if (i < n4) {
        float4 v = ((const float4*)x)[i];
        f16x2 a, b;
        a[0] = (_Float16)v.x; a[1] = (_Float16)v.y;
        b[0] = (_Float16)v.z; b[1] = (_Float16)v.w;
        ((f16x2*)x16)[i * 2] = a;
        ((f16x2*)x16)[i * 2 + 1] = b;
    }
}

// ---------------------------------------------------------------------------
// Fused MFMA GEMM: t = x @ Wt.T, p = x @ Wp.T in fp16 (fp32 accumulate).
// EXACT round-4 verified structure (sequential per-step load->compute).
// Block = 4 waves, 128 rows; wave owns 32 cols of BOTH outputs; all B frags
// live in regs for the whole block. No LDS, no barriers.
// C/D layout: col = lane&15, row = (lane>>4)*4 + reg.
// ---------------------------------------------------------------------------

__global__ __launch_bounds__(256) void mfma_gemm_kernel(
        const _Float16* __restrict__ x16,
        const _Float16* __restrict__ wt, const _Float16* __restrict__ wp,
        _Float16* __restrict__ t16, _Float16* __restrict__ p16, int M) {
    int lane = threadIdx.x & 63;
    int l16 = lane & 15;
    int quad = lane >> 4;
    int cn0 = (threadIdx.x >> 6) * 32;

    f16x8 bt[2][4], bp[2][4];
#pragma unroll
    for (int ct = 0; ct < 2; ++ct) {
        int col = cn0 + ct * 16 + l16;
#pragma unroll
        for (int kk = 0; kk < 4; ++kk) {
            int k = kk * 32 + quad * 8;
            bt[ct][kk] = *(const f16x8*)(wt + (size_t)col * FEAT + k);
            bp[ct][kk] = *(const f16x8*)(wp + (size_t)col * FEAT + k);
        }
    }

    int rbase0 = blockIdx.x * 128;
#pragma unroll 1
    for (int rs = 0; rs < 8; ++rs) {
        int rbase = rbase0 + rs * 16;
        int row = rbase + l16;
        int rowc = (row < M) ? row : (M - 1);
        f16x8 a[4];
#pragma unroll
        for (int kk = 0; kk < 4; ++kk)
            a[kk] = *(const f16x8*)(x16 + (size_t)rowc * FEAT + kk * 32 + quad * 8);

        f32x4 accT[2] = {{0.f, 0.f, 0.f, 0.f}, {0.f, 0.f, 0.f, 0.f}};
        f32x4 accP[2] = {{0.f, 0.f, 0.f, 0.f}, {0.f, 0.f, 0.f, 0.f}};
#pragma unroll
        for (int kk = 0; kk < 4; ++kk) {
#pragma unroll
            for (int ct = 0; ct < 2; ++ct) {
                accT[ct] = __builtin_amdgcn_mfma_f32_16x16x32_f16(a[kk], bt[ct][kk], accT[ct], 0, 0, 0);
                accP[ct] = __builtin_amdgcn_mfma_f32_16x16x32_f16(a[kk], bp[ct][kk], accP[ct], 0, 0, 0);
            }
        }
#pragma unroll
        for (int ct = 0; ct < 2; ++ct) {
            int col = cn0 + ct * 16 + l16;
#pragma unroll
            for (int r = 0; r < 4; ++r) {
                int ro = rbase + quad * 4 + r;
                if (ro < M) {
                    t16[(size_t)ro * FEAT + col] = (_Float16)accT[ct][r];
                    p16[(size_t)ro * FEAT + col] = (_Float16)accP[ct][r];
                }
            }
        }
    }
}

// ---------------------------------------------------------------------------
// Aggregation + epilogue. One wave per node. Lane = (g = lane>>4 edge slot,
// c = lane&15 feature chunk of 8 fp16). One f16x8 load gathers 4 full 256 B
// rows per instruction (one per slot). BRANCHLESS: all indices clamped to
// valid edges (duplicates are idempotent under max). Slot-maxes combined with
// 2 register-only shfl_xor rounds; epilogue on slot-0 lanes.
// o = relu( max_e t[src_e] - t[i] + tb + pb + p[i] ), 0 for edgeless nodes.
// ---------------------------------------------------------------------------

static __device__ __forceinline__ f16x8 vmax8(f16x8 a, f16x8 b) {
#pragma unroll
    for (int i = 0; i < 8; ++i) a[i] = (a[i] > b[i]) ? a[i] : b[i];
    return a;
}

static __device__ __forceinline__ f16x8 shflxor8(f16x8 v, int mask) {
    union { f16x8 h; int i[4]; } u;
    u.h = v;
#pragma unroll
    for (int k = 0; k < 4; ++k) u.i[k] = __shfl_xor(u.i[k], mask, 64);
    return u.h;
}

__global__ __launch_bounds__(256) void agg_kernel(
        const _Float16* __restrict__ t16, const _Float16* __restrict__ p16,
        const float* __restrict__ tb, const float* __restrict__ pb,
        const int* __restrict__ row_ptr, const int* __restrict__ esrc,
        float* __restrict__ outf, _Float16* __restrict__ ox, int N) {
    int wv = threadIdx.x >> 6;
    int lane = threadIdx.x & 63;
    int node = blockIdx.x * 4 + wv;
    if (node >= N) return;

    int g = lane >> 4;
    int c = lane & 15;

    int beg = row_ptr[node];
    int end = row_ptr[node + 1];

    if (beg >= end) {  // edgeless: zeros (segment_max -inf -> 0 -> relu -> 0)
        if (outf && g == 0) {
            float4 z = make_float4(0.f, 0.f, 0.f, 0.f);
            ((float4*)(outf + (size_t)node * FEAT + c * 8))[0] = z;
            ((float4*)(outf + (size_t)node * FEAT + c * 8))[1] = z;
        }
        if (ox && g == 0) {
            f16x8 z = {};
            *(f16x8*)(ox + (size_t)node * FEAT + c * 8) = z;
        }
        return;
    }

    const _Float16 NEGINF = (_Float16)(-65504.0f);
    f16x8 m;
#pragma unroll
    for (int i = 0; i < 8; ++i) m[i] = NEGINF;

    for (int base = beg; base < end; base += 64) {
        int n = end - base;
        if (n > 64) n = 64;
        int nm1 = n - 1;
        int li = (lane < n) ? lane : nm1;          // clamped -> always valid
        int myidx = esrc[base + li];                // one coalesced load
        for (int j = 0; j < n; j += 4) {
            int sl = j + g;
            if (sl > nm1) sl = nm1;                 // clamp (duplicate edge ok)
            int idx = __shfl(myidx, sl);
            f16x8 v = *(const f16x8*)(t16 + (size_t)idx * FEAT + c * 8);
            m = vmax8(m, v);
        }
    }

    // combine the 4 edge slots (butterfly over lane bits 4 and 5)
    m = vmax8(m, shflxor8(m, 16));
    m = vmax8(m, shflxor8(m, 32));

    // epilogue on slot-0 lanes (16 lanes x 8 features = full row)
    if (g == 0) {
        f16x8 ti = *(const f16x8*)(t16 + (size_t)node * FEAT + c * 8);
        f16x8 pi = *(const f16x8*)(p16 + (size_t)node * FEAT + c * 8);
        float4 tb0 = ((const float4*)(tb + c * 8))[0];
        float4 tb1 = ((const float4*)(tb + c * 8))[1];
        float4 pb0 = ((const float4*)(pb + c * 8))[0];
        float4 pb1 = ((const float4*)(pb + c * 8))[1];
        float bias[8] = {tb0.x + pb0.x, tb0.y + pb0.y, tb0.z + pb0.z, tb0.w + pb0.w,
                         tb1.x + pb1.x, tb1.y + pb1.y, tb1.z + pb1.z, tb1.w + pb1.w};
        float o[8];
#pragma unroll
        for (int i = 0; i < 8; ++i)
            o[i] = fmaxf((float)m[i] - (float)ti[i] + bias[i] + (float)pi[i], 0.f);

        if (outf) {
            float4 o0 = make_float4(o[0], o[1], o[2], o[3]);
            float4 o1 = make_float4(o[4], o[5], o[6], o[7]);
            ((float4*)(outf + (size_t)node * FEAT + c * 8))[0] = o0;
            ((float4*)(outf + (size_t)node * FEAT + c * 8))[1] = o1;
        }
        if (ox) {
            f16x8 oh;
#pragma unroll
            for (int i = 0; i < 8; ++i) oh[i] = (_Float16)o[i];
            *(f16x8*)(ox + (size_t)node * FEAT + c * 8) = oh;
        }
    }
}

// ---------------------------------------------------------------------------

extern "C" void kernel_launch(void* const* d_in, const int* in_sizes, int n_in,
                              void* d_out, int out_size, void* d_ws, size_t ws_size,
                              hipStream_t stream) {
    const float* feats   = (const float*)d_in[0];
    const int*   src     = (const int*)d_in[1];
    const int*   dst     = (const int*)d_in[2];
    const float* theta_w = (const float*)d_in[3];
    const float* theta_b = (const float*)d_in[4];
    const float* phi_w   = (const float*)d_in[5];
    const float* phi_b   = (const float*)d_in[6];

    const int N = in_sizes[0] / FEAT;
    const int E = in_sizes[1];
    const int L = in_sizes[3] / (FEAT * FEAT);

    char* ws = (char*)d_ws;
    size_t off = 0;
    auto alloc = [&](size_t bytes) -> void* {
        void* ptr = ws + off;
        off = (off + bytes + 255) & ~(size_t)255;
        return ptr;
    };
    _Float16* t16 = (_Float16*)alloc((size_t)N * FEAT * 2);
    _Float16* p16 = (_Float16*)alloc((size_t)N * FEAT * 2);
    _Float16* x16 = (_Float16*)alloc((size_t)N * FEAT * 2);
    _Float16* wt16 = (_Float16*)alloc((size_t)L * FEAT * FEAT * 2);
    _Float16* wp16 = (_Float16*)alloc((size_t)L * FEAT * FEAT * 2);
    int* deg     = (int*)alloc((size_t)N * sizeof(int));
    int* fill    = (int*)alloc((size_t)N * sizeof(int));
    int* row_ptr = (int*)alloc((size_t)(N + 1) * sizeof(int));
    int* esrc    = (int*)alloc((size_t)E * sizeof(int));
    int* bsum    = (int*)alloc(2048 * sizeof(int));
    int* boff    = (int*)alloc(2048 * sizeof(int));
    (void)ws_size;

    hipMemsetAsync(deg, 0, (size_t)N * sizeof(int), stream);
    hipMemsetAsync(fill, 0, (size_t)N * sizeof(int), stream);

    int eb = (E + 255) / 256;
    int nb = (N + 1023) >> 10;
    hist_kernel<<<eb, 256, 0, stream>>>(dst, deg, E);
    scan1_kernel<<<nb, 1024, 0, stream>>>(deg, row_ptr, bsum, N);
    scan2_kernel<<<1, 1024, 0, stream>>>(bsum, boff, row_ptr, nb, N, E);
    scan3_kernel<<<(N + 255) / 256, 256, 0, stream>>>(row_ptr, boff, N);
    scatter_kernel<<<eb, 256, 0, stream>>>(src, dst, row_ptr, fill, esrc, E);

    int wn = L * FEAT * FEAT;
    wcvt_kernel<<<(wn + 255) / 256, 256, 0, stream>>>(theta_w, phi_w, wt16, wp16, wn);
    int xn4 = N * FEAT / 4;
    xcvt_kernel<<<(xn4 + 255) / 256, 256, 0, stream>>>(feats, x16, xn4);

    int gb = (N + 127) / 128;
    for (int l = 0; l < L; ++l) {
        mfma_gemm_kernel<<<gb, 256, 0, stream>>>(
            x16,
            wt16 + (size_t)l * FEAT * FEAT,
            wp16 + (size_t)l * FEAT * FEAT,
            t16, p16, N);

        bool last = (l == L - 1);
        agg_kernel<<<(N + 3) / 4, 256, 0, stream>>>(
            t16, p16,
            theta_b + (size_t)l * FEAT,
            phi_b + (size_t)l * FEAT,
            row_ptr, esrc,
            last ? (float*)d_out : nullptr,
            last ? nullptr : x16,   // in-place: x16 fully consumed before agg runs
            N);
    }
}

// Round 7
// 341.507 us; speedup vs baseline: 1.0509x; 1.0509x over previous
//
#include <hip/hip_runtime.h>

#define FEAT 128

typedef __attribute__((ext_vector_type(8))) _Float16 f16x8;
typedef __attribute__((ext_vector_type(2))) _Float16 f16x2;
typedef __attribute__((ext_vector_type(4))) float f32x4;

static __device__ __forceinline__ int wave_incl_scan(int v, int lane) {
#pragma unroll
    for (int off = 1; off < 64; off <<= 1) {
        int u = __shfl_up(v, off, 64);
        if (lane >= off) v += u;
    }
    return v;
}

// ---------------------------------------------------------------------------
// CSR build: histogram -> 3-phase parallel scan -> scatter.
// ---------------------------------------------------------------------------

__global__ void hist_kernel(const int* __restrict__ dst, int* __restrict__ deg, int E) {
    int e = blockIdx.x * blockDim.x + threadIdx.x;
    if (e < E) atomicAdd(&deg[dst[e]], 1);
}

__global__ __launch_bounds__(1024) void scan1_kernel(const int* __restrict__ deg,
                                                     int* __restrict__ row_ptr,
                                                     int* __restrict__ bsum, int N) {
    int i = blockIdx.x * 1024 + threadIdx.x;
    int lane = threadIdx.x & 63;
    int w = threadIdx.x >> 6;
    int v = (i < N) ? deg[i] : 0;
    int inc = wave_incl_scan(v, lane);
    __shared__ int wsum[16];
    if (lane == 63) wsum[w] = inc;
    __syncthreads();
    if (w == 0) {
        int s = (lane < 16) ? wsum[lane] : 0;
        int si = wave_incl_scan(s, lane);
        if (lane < 16) wsum[lane] = si - s;
    }
    __syncthreads();
    int exc = inc - v + wsum[w];
    if (i < N) row_ptr[i] = exc;
    if (threadIdx.x == 1023) bsum[blockIdx.x] = exc + v;
}

__global__ __launch_bounds__(1024) void scan2_kernel(const int* __restrict__ bsum,
                                                     int* __restrict__ boff,
                                                     int* __restrict__ row_ptr,
                                                     int nb, int N, int E) {
    int tid = threadIdx.x;
    int lane = tid & 63;
    int w = tid >> 6;
    int v = (tid < nb) ? bsum[tid] : 0;
    int inc = wave_incl_scan(v, lane);
    __shared__ int wsum[16];
    if (lane == 63) wsum[w] = inc;
    __syncthreads();
    if (w == 0) {
        int s = (lane < 16) ? wsum[lane] : 0;
        int si = wave_incl_scan(s, lane);
        if (lane < 16) wsum[lane] = si - s;
    }
    __syncthreads();
    if (tid < nb) boff[tid] = inc - v + wsum[w];
    if (tid == 0) row_ptr[N] = E;
}

__global__ void scan3_kernel(int* __restrict__ row_ptr, const int* __restrict__ boff, int N) {
    int i = blockIdx.x * blockDim.x + threadIdx.x;
    if (i < N) row_ptr[i] += boff[i >> 10];
}

__global__ void scatter_kernel(const int* __restrict__ src, const int* __restrict__ dst,
                               const int* __restrict__ row_ptr, int* __restrict__ fill,
                               int* __restrict__ esrc, int E) {
    int e = blockIdx.x * blockDim.x + threadIdx.x;
    if (e < E) {
        int d = dst[e];
        int pos = row_ptr[d] + atomicAdd(&fill[d], 1);
        esrc[pos] = src[e];
    }
}

// ---------------------------------------------------------------------------
// fp32 -> fp16 converts (weights once, feats once) + per-layer bias sums
// (bias[l][j] = theta_b[l][j] + phi_b[l][j], fp32).
// ---------------------------------------------------------------------------

__global__ void wcvt_kernel(const float* __restrict__ tw, const float* __restrict__ pw,
                            const float* __restrict__ tb, const float* __restrict__ pb,
                            _Float16* __restrict__ wt, _Float16* __restrict__ wp,
                            float* __restrict__ bsum, int n, int nbias) {
    int i = blockIdx.x * blockDim.x + threadIdx.x;
    if (i < n) { wt[i] = (_Float16)tw[i]; wp[i] = (_Float16)pw[i]; }
    if (i < nbias) bsum[i] = tb[i] + pb[i];
}

__global__ void xcvt_kernel(const float* __restrict__ x, _Float16* __restrict__ x16, int n4) {
    int i = blockIdx.x * blockDim.x + threadIdx.x;
    if (i < n4) {
        float4 v = ((const float4*)x)[i];
        f16x2 a, b;
        a[0] = (_Float16)v.x; a[1] = (_Float16)v.y;
        b[0] = (_Float16)v.z; b[1] = (_Float16)v.w;
        ((f16x2*)x16)[i * 2] = a;
        ((f16x2*)x16)[i * 2 + 1] = b;
    }
}

// ---------------------------------------------------------------------------
// Fused MFMA GEMM: t = x @ Wt.T and q = x @ Wp.T - t + (tb+pb), fp16 out.
// Round-6-verified core; only the epilogue changed (q-fusion).
// Block = 4 waves, 128 rows; wave owns 32 cols of BOTH outputs; all B frags
// live in regs for the whole block. No LDS, no barriers.
// C/D layout: col = lane&15, row = (lane>>4)*4 + reg.
// ---------------------------------------------------------------------------

__global__ __launch_bounds__(256) void mfma_gemm_kernel(
        const _Float16* __restrict__ x16,
        const _Float16* __restrict__ wt, const _Float16* __restrict__ wp,
        const float* __restrict__ bias,
        _Float16* __restrict__ t16, _Float16* __restrict__ q16, int M) {
    int lane = threadIdx.x & 63;
    int l16 = lane & 15;
    int quad = lane >> 4;
    int cn0 = (threadIdx.x >> 6) * 32;

    f16x8 bt[2][4], bp[2][4];
    float biasv[2];
#pragma unroll
    for (int ct = 0; ct < 2; ++ct) {
        int col = cn0 + ct * 16 + l16;
        biasv[ct] = bias[col];
#pragma unroll
        for (int kk = 0; kk < 4; ++kk) {
            int k = kk * 32 + quad * 8;
            bt[ct][kk] = *(const f16x8*)(wt + (size_t)col * FEAT + k);
            bp[ct][kk] = *(const f16x8*)(wp + (size_t)col * FEAT + k);
        }
    }

    int rbase0 = blockIdx.x * 128;
#pragma unroll 1
    for (int rs = 0; rs < 8; ++rs) {
        int rbase = rbase0 + rs * 16;
        int row = rbase + l16;
        int rowc = (row < M) ? row : (M - 1);
        f16x8 a[4];
#pragma unroll
        for (int kk = 0; kk < 4; ++kk)
            a[kk] = *(const f16x8*)(x16 + (size_t)rowc * FEAT + kk * 32 + quad * 8);

        f32x4 accT[2] = {{0.f, 0.f, 0.f, 0.f}, {0.f, 0.f, 0.f, 0.f}};
        f32x4 accP[2] = {{0.f, 0.f, 0.f, 0.f}, {0.f, 0.f, 0.f, 0.f}};
#pragma unroll
        for (int kk = 0; kk < 4; ++kk) {
#pragma unroll
            for (int ct = 0; ct < 2; ++ct) {
                accT[ct] = __builtin_amdgcn_mfma_f32_16x16x32_f16(a[kk], bt[ct][kk], accT[ct], 0, 0, 0);
                accP[ct] = __builtin_amdgcn_mfma_f32_16x16x32_f16(a[kk], bp[ct][kk], accP[ct], 0, 0, 0);
            }
        }
#pragma unroll
        for (int ct = 0; ct < 2; ++ct) {
            int col = cn0 + ct * 16 + l16;
#pragma unroll
            for (int r = 0; r < 4; ++r) {
                int ro = rbase + quad * 4 + r;
                if (ro < M) {
                    t16[(size_t)ro * FEAT + col] = (_Float16)accT[ct][r];
                    q16[(size_t)ro * FEAT + col] =
                        (_Float16)(accP[ct][r] - accT[ct][r] + biasv[ct]);
                }
            }
        }
    }
}

// ---------------------------------------------------------------------------
// Aggregation + epilogue. One wave per node. Lane = (g = lane>>4 edge slot,
// c = lane&15 feature chunk of 8 fp16). One f16x8 load gathers 4 full 256 B
// rows per instruction. Inner loop unrolled x2 (8 rows in flight) with NO
// guards in the unrolled body (j+8<=n makes both slots valid); clamped 4-wide
// tail. Slot-maxes combined with 2 register-only shfl_xor rounds.
// out = relu( max_e t[src_e] + q[i] ), 0 for edgeless nodes.
// ---------------------------------------------------------------------------

static __device__ __forceinline__ f16x8 vmax8(f16x8 a, f16x8 b) {
#pragma unroll
    for (int i = 0; i < 8; ++i) a[i] = (a[i] > b[i]) ? a[i] : b[i];
    return a;
}

static __device__ __forceinline__ f16x8 shflxor8(f16x8 v, int mask) {
    union { f16x8 h; int i[4]; } u;
    u.h = v;
#pragma unroll
    for (int k = 0; k < 4; ++k) u.i[k] = __shfl_xor(u.i[k], mask, 64);
    return u.h;
}

__global__ __launch_bounds__(256) void agg_kernel(
        const _Float16* __restrict__ t16, const _Float16* __restrict__ q16,
        const int* __restrict__ row_ptr, const int* __restrict__ esrc,
        float* __restrict__ outf, _Float16* __restrict__ ox, int N) {
    int wv = threadIdx.x >> 6;
    int lane = threadIdx.x & 63;
    int node = blockIdx.x * 4 + wv;
    if (node >= N) return;

    int g = lane >> 4;
    int c = lane & 15;

    int beg = row_ptr[node];
    int end = row_ptr[node + 1];

    if (beg >= end) {  // edgeless: zeros (segment_max -inf -> 0 -> relu -> 0)
        if (outf && g == 0) {
            float4 z = make_float4(0.f, 0.f, 0.f, 0.f);
            ((float4*)(outf + (size_t)node * FEAT + c * 8))[0] = z;
            ((float4*)(outf + (size_t)node * FEAT + c * 8))[1] = z;
        }
        if (ox && g == 0) {
            f16x8 z = {};
            *(f16x8*)(ox + (size_t)node * FEAT + c * 8) = z;
        }
        return;
    }

    const _Float16 NEGINF = (_Float16)(-65504.0f);
    f16x8 m;
#pragma unroll
    for (int i = 0; i < 8; ++i) m[i] = NEGINF;

    for (int base = beg; base < end; base += 64) {
        int n = end - base;
        if (n > 64) n = 64;
        int nm1 = n - 1;
        int li = (lane < n) ? lane : nm1;          // clamped -> always valid
        int myidx = esrc[base + li];                // one coalesced load
        int j = 0;
        for (; j + 8 <= n; j += 8) {                // guard-free: both slots valid
            int i0 = __shfl(myidx, j + g);
            int i1 = __shfl(myidx, j + 4 + g);
            f16x8 v0 = *(const f16x8*)(t16 + (size_t)i0 * FEAT + c * 8);
            f16x8 v1 = *(const f16x8*)(t16 + (size_t)i1 * FEAT + c * 8);
            m = vmax8(m, vmax8(v0, v1));
        }
        for (; j < n; j += 4) {                     // clamped tail
            int sl = j + g;
            if (sl > nm1) sl = nm1;                 // duplicate edge ok under max
            int idx = __shfl(myidx, sl);
            f16x8 v = *(const f16x8*)(t16 + (size_t)idx * FEAT + c * 8);
            m = vmax8(m, v);
        }
    }

    // combine the 4 edge slots (butterfly over lane bits 4 and 5)
    m = vmax8(m, shflxor8(m, 16));
    m = vmax8(m, shflxor8(m, 32));

    // epilogue on slot-0 lanes (16 lanes x 8 features = full row)
    if (g == 0) {
        f16x8 qi = *(const f16x8*)(q16 + (size_t)node * FEAT + c * 8);
        float o[8];
#pragma unroll
        for (int i = 0; i < 8; ++i)
            o[i] = fmaxf((float)m[i] + (float)qi[i], 0.f);

        if (outf) {
            float4 o0 = make_float4(o[0], o[1], o[2], o[3]);
            float4 o1 = make_float4(o[4], o[5], o[6], o[7]);
            ((float4*)(outf + (size_t)node * FEAT + c * 8))[0] = o0;
            ((float4*)(outf + (size_t)node * FEAT + c * 8))[1] = o1;
        }
        if (ox) {
            f16x8 oh;
#pragma unroll
            for (int i = 0; i < 8; ++i) oh[i] = (_Float16)o[i];
            *(f16x8*)(ox + (size_t)node * FEAT + c * 8) = oh;
        }
    }
}

// ---------------------------------------------------------------------------

extern "C" void kernel_launch(void* const* d_in, const int* in_sizes, int n_in,
                              void* d_out, int out_size, void* d_ws, size_t ws_size,
                              hipStream_t stream) {
    const float* feats   = (const float*)d_in[0];
    const int*   src     = (const int*)d_in[1];
    const int*   dst     = (const int*)d_in[2];
    const float* theta_w = (const float*)d_in[3];
    const float* theta_b = (const float*)d_in[4];
    const float* phi_w   = (const float*)d_in[5];
    const float* phi_b   = (const float*)d_in[6];

    const int N = in_sizes[0] / FEAT;
    const int E = in_sizes[1];
    const int L = in_sizes[3] / (FEAT * FEAT);

    char* ws = (char*)d_ws;
    size_t off = 0;
    auto alloc = [&](size_t bytes) -> void* {
        void* ptr = ws + off;
        off = (off + bytes + 255) & ~(size_t)255;
        return ptr;
    };
    _Float16* t16 = (_Float16*)alloc((size_t)N * FEAT * 2);
    _Float16* q16 = (_Float16*)alloc((size_t)N * FEAT * 2);
    _Float16* x16 = (_Float16*)alloc((size_t)N * FEAT * 2);
    _Float16* wt16 = (_Float16*)alloc((size_t)L * FEAT * FEAT * 2);
    _Float16* wp16 = (_Float16*)alloc((size_t)L * FEAT * FEAT * 2);
    float* bsum_b = (float*)alloc((size_t)L * FEAT * sizeof(float));
    int* deg     = (int*)alloc((size_t)N * sizeof(int));
    int* fill    = (int*)alloc((size_t)N * sizeof(int));
    int* row_ptr = (int*)alloc((size_t)(N + 1) * sizeof(int));
    int* esrc    = (int*)alloc((size_t)E * sizeof(int));
    int* bsum    = (int*)alloc(2048 * sizeof(int));
    int* boff    = (int*)alloc(2048 * sizeof(int));
    (void)ws_size;

    hipMemsetAsync(deg, 0, (size_t)N * sizeof(int), stream);
    hipMemsetAsync(fill, 0, (size_t)N * sizeof(int), stream);

    int eb = (E + 255) / 256;
    int nb = (N + 1023) >> 10;
    hist_kernel<<<eb, 256, 0, stream>>>(dst, deg, E);
    scan1_kernel<<<nb, 1024, 0, stream>>>(deg, row_ptr, bsum, N);
    scan2_kernel<<<1, 1024, 0, stream>>>(bsum, boff, row_ptr, nb, N, E);
    scan3_kernel<<<(N + 255) / 256, 256, 0, stream>>>(row_ptr, boff, N);
    scatter_kernel<<<eb, 256, 0, stream>>>(src, dst, row_ptr, fill, esrc, E);

    int wn = L * FEAT * FEAT;
    wcvt_kernel<<<(wn + 255) / 256, 256, 0, stream>>>(
        theta_w, phi_w, theta_b, phi_b, wt16, wp16, bsum_b, wn, L * FEAT);
    int xn4 = N * FEAT / 4;
    xcvt_kernel<<<(xn4 + 255) / 256, 256, 0, stream>>>(feats, x16, xn4);

    int gb = (N + 127) / 128;
    for (int l = 0; l < L; ++l) {
        mfma_gemm_kernel<<<gb, 256, 0, stream>>>(
            x16,
            wt16 + (size_t)l * FEAT * FEAT,
            wp16 + (size_t)l * FEAT * FEAT,
            bsum_b + (size_t)l * FEAT,
            t16, q16, N);

        bool last = (l == L - 1);
        agg_kernel<<<(N + 3) / 4, 256, 0, stream>>>(
            t16, q16,
            row_ptr, esrc,
            last ? (float*)d_out : nullptr,
            last ? nullptr : x16,   // in-place: x16 fully consumed before agg runs
            N);
    }
}

// Round 8
// 338.936 us; speedup vs baseline: 1.0589x; 1.0076x over previous
//
#include <hip/hip_runtime.h>

#define FEAT 128

typedef __attribute__((ext_vector_type(8))) _Float16 f16x8;
typedef __attribute__((ext_vector_type(2))) _Float16 f16x2;
typedef __attribute__((ext_vector_type(4))) float f32x4;

static __device__ __forceinline__ int wave_incl_scan(int v, int lane) {
#pragma unroll
    for (int off = 1; off < 64; off <<= 1) {
        int u = __shfl_up(v, off, 64);
        if (lane >= off) v += u;
    }
    return v;
}

// ---------------------------------------------------------------------------
// CSR build: histogram -> 3-phase parallel scan -> scatter (scatter fused
// with layer-0 GEMM below).
// ---------------------------------------------------------------------------

__global__ void hist_kernel(const int* __restrict__ dst, int* __restrict__ deg, int E) {
    int e = blockIdx.x * blockDim.x + threadIdx.x;
    if (e < E) atomicAdd(&deg[dst[e]], 1);
}

__global__ __launch_bounds__(1024) void scan1_kernel(const int* __restrict__ deg,
                                                     int* __restrict__ row_ptr,
                                                     int* __restrict__ bsum, int N) {
    int i = blockIdx.x * 1024 + threadIdx.x;
    int lane = threadIdx.x & 63;
    int w = threadIdx.x >> 6;
    int v = (i < N) ? deg[i] : 0;
    int inc = wave_incl_scan(v, lane);
    __shared__ int wsum[16];
    if (lane == 63) wsum[w] = inc;
    __syncthreads();
    if (w == 0) {
        int s = (lane < 16) ? wsum[lane] : 0;
        int si = wave_incl_scan(s, lane);
        if (lane < 16) wsum[lane] = si - s;
    }
    __syncthreads();
    int exc = inc - v + wsum[w];
    if (i < N) row_ptr[i] = exc;
    if (threadIdx.x == 1023) bsum[blockIdx.x] = exc + v;
}

__global__ __launch_bounds__(1024) void scan2_kernel(const int* __restrict__ bsum,
                                                     int* __restrict__ boff,
                                                     int* __restrict__ row_ptr,
                                                     int nb, int N, int E) {
    int tid = threadIdx.x;
    int lane = tid & 63;
    int w = tid >> 6;
    int v = (tid < nb) ? bsum[tid] : 0;
    int inc = wave_incl_scan(v, lane);
    __shared__ int wsum[16];
    if (lane == 63) wsum[w] = inc;
    __syncthreads();
    if (w == 0) {
        int s = (lane < 16) ? wsum[lane] : 0;
        int si = wave_incl_scan(s, lane);
        if (lane < 16) wsum[lane] = si - s;
    }
    __syncthreads();
    if (tid < nb) boff[tid] = inc - v + wsum[w];
    if (tid == 0) row_ptr[N] = E;
}

__global__ void scan3_kernel(int* __restrict__ row_ptr, const int* __restrict__ boff, int N) {
    int i = blockIdx.x * blockDim.x + threadIdx.x;
    if (i < N) row_ptr[i] += boff[i >> 10];
}

// ---------------------------------------------------------------------------
// fp32 -> fp16 converts (weights once, feats once) + per-layer bias sums.
// ---------------------------------------------------------------------------

__global__ void wcvt_kernel(const float* __restrict__ tw, const float* __restrict__ pw,
                            const float* __restrict__ tb, const float* __restrict__ pb,
                            _Float16* __restrict__ wt, _Float16* __restrict__ wp,
                            float* __restrict__ bsum, int n, int nbias) {
    int i = blockIdx.x * blockDim.x + threadIdx.x;
    if (i < n) { wt[i] = (_Float16)tw[i]; wp[i] = (_Float16)pw[i]; }
    if (i < nbias) bsum[i] = tb[i] + pb[i];
}

__global__ void xcvt_kernel(const float* __restrict__ x, _Float16* __restrict__ x16, int n4) {
    int i = blockIdx.x * blockDim.x + threadIdx.x;
    if (i < n4) {
        float4 v = ((const float4*)x)[i];
        f16x2 a, b;
        a[0] = (_Float16)v.x; a[1] = (_Float16)v.y;
        b[0] = (_Float16)v.z; b[1] = (_Float16)v.w;
        ((f16x2*)x16)[i * 2] = a;
        ((f16x2*)x16)[i * 2 + 1] = b;
    }
}

// ---------------------------------------------------------------------------
// Fused MFMA GEMM body (round-7 verified): t = x @ Wt.T,
// q = x @ Wp.T - t + (tb+pb), fp16 out. Block = 4 waves, 128 rows; wave owns
// 32 cols; all B frags in regs. No LDS, no barriers.
// C/D layout: col = lane&15, row = (lane>>4)*4 + reg.
// ---------------------------------------------------------------------------

static __device__ __forceinline__ void gemm_body(
        int bx,
        const _Float16* __restrict__ x16,
        const _Float16* __restrict__ wt, const _Float16* __restrict__ wp,
        const float* __restrict__ bias,
        _Float16* __restrict__ t16, _Float16* __restrict__ q16, int M) {
    int lane = threadIdx.x & 63;
    int l16 = lane & 15;
    int quad = lane >> 4;
    int cn0 = (threadIdx.x >> 6) * 32;

    f16x8 bt[2][4], bp[2][4];
    float biasv[2];
#pragma unroll
    for (int ct = 0; ct < 2; ++ct) {
        int col = cn0 + ct * 16 + l16;
        biasv[ct] = bias[col];
#pragma unroll
        for (int kk = 0; kk < 4; ++kk) {
            int k = kk * 32 + quad * 8;
            bt[ct][kk] = *(const f16x8*)(wt + (size_t)col * FEAT + k);
            bp[ct][kk] = *(const f16x8*)(wp + (size_t)col * FEAT + k);
        }
    }

    int rbase0 = bx * 128;
#pragma unroll 1
    for (int rs = 0; rs < 8; ++rs) {
        int rbase = rbase0 + rs * 16;
        int row = rbase + l16;
        int rowc = (row < M) ? row : (M - 1);
        f16x8 a[4];
#pragma unroll
        for (int kk = 0; kk < 4; ++kk)
            a[kk] = *(const f16x8*)(x16 + (size_t)rowc * FEAT + kk * 32 + quad * 8);

        f32x4 accT[2] = {{0.f, 0.f, 0.f, 0.f}, {0.f, 0.f, 0.f, 0.f}};
        f32x4 accP[2] = {{0.f, 0.f, 0.f, 0.f}, {0.f, 0.f, 0.f, 0.f}};
#pragma unroll
        for (int kk = 0; kk < 4; ++kk) {
#pragma unroll
            for (int ct = 0; ct < 2; ++ct) {
                accT[ct] = __builtin_amdgcn_mfma_f32_16x16x32_f16(a[kk], bt[ct][kk], accT[ct], 0, 0, 0);
                accP[ct] = __builtin_amdgcn_mfma_f32_16x16x32_f16(a[kk], bp[ct][kk], accP[ct], 0, 0, 0);
            }
        }
#pragma unroll
        for (int ct = 0; ct < 2; ++ct) {
            int col = cn0 + ct * 16 + l16;
#pragma unroll
            for (int r = 0; r < 4; ++r) {
                int ro = rbase + quad * 4 + r;
                if (ro < M) {
                    t16[(size_t)ro * FEAT + col] = (_Float16)accT[ct][r];
                    q16[(size_t)ro * FEAT + col] =
                        (_Float16)(accP[ct][r] - accT[ct][r] + biasv[ct]);
                }
            }
        }
    }
}

__global__ __launch_bounds__(256) void mfma_gemm_kernel(
        const _Float16* __restrict__ x16,
        const _Float16* __restrict__ wt, const _Float16* __restrict__ wp,
        const float* __restrict__ bias,
        _Float16* __restrict__ t16, _Float16* __restrict__ q16, int M) {
    gemm_body(blockIdx.x, x16, wt, wp, bias, t16, q16, M);
}

// Layer-0 GEMM fused with the CSR scatter: blocks [0,gb) do the GEMM, blocks
// [gb,..) do the scatter. Both depend only on already-complete producers
// (x16/weights/bias and row_ptr/fill). Hides the scatter's atomics under the
// GEMM's MFMA work.
__global__ __launch_bounds__(256) void fused0_kernel(
        const _Float16* __restrict__ x16,
        const _Float16* __restrict__ wt, const _Float16* __restrict__ wp,
        const float* __restrict__ bias,
        _Float16* __restrict__ t16, _Float16* __restrict__ q16, int M, int gb,
        const int* __restrict__ src, const int* __restrict__ dst,
        const int* __restrict__ row_ptr, int* __restrict__ fill,
        int* __restrict__ esrc, int E) {
    if ((int)blockIdx.x < gb) {
        gemm_body(blockIdx.x, x16, wt, wp, bias, t16, q16, M);
    } else {
        int e = (blockIdx.x - gb) * 256 + threadIdx.x;
        if (e < E) {
            int d = dst[e];
            int pos = row_ptr[d] + atomicAdd(&fill[d], 1);
            esrc[pos] = src[e];
        }
    }
}

// ---------------------------------------------------------------------------
// Aggregation + epilogue. One wave per node. Lane = (g = lane>>4 edge slot,
// c = lane&15 feature chunk of 8 fp16). Per 16-edge group: 4 INDEPENDENT
// load registers + 4 INDEPENDENT accumulators with wave-uniform guards
// (n identical across the wave), so all 4 row-gathers are in flight before
// the first vmax waits. Clamped slots duplicate edges (idempotent under max).
// Slot-maxes combined with 2 register-only shfl_xor rounds.
// out = relu( max_e t[src_e] + q[i] ), 0 for edgeless nodes.
// ---------------------------------------------------------------------------

static __device__ __forceinline__ f16x8 vmax8(f16x8 a, f16x8 b) {
#pragma unroll
    for (int i = 0; i < 8; ++i) a[i] = (a[i] > b[i]) ? a[i] : b[i];
    return a;
}

static __device__ __forceinline__ f16x8 shflxor8(f16x8 v, int mask) {
    union { f16x8 h; int i[4]; } u;
    u.h = v;
#pragma unroll
    for (int k = 0; k < 4; ++k) u.i[k] = __shfl_xor(u.i[k], mask, 64);
    return u.h;
}

__global__ __launch_bounds__(256) void agg_kernel(
        const _Float16* __restrict__ t16, const _Float16* __restrict__ q16,
        const int* __restrict__ row_ptr, const int* __restrict__ esrc,
        float* __restrict__ outf, _Float16* __restrict__ ox, int N) {
    int wv = threadIdx.x >> 6;
    int lane = threadIdx.x & 63;
    int node = blockIdx.x * 4 + wv;
    if (node >= N) return;

    int g = lane >> 4;
    int c = lane & 15;

    int beg = row_ptr[node];
    int end = row_ptr[node + 1];

    if (beg >= end) {  // edgeless: zeros (segment_max -inf -> 0 -> relu -> 0)
        if (outf && g == 0) {
            float4 z = make_float4(0.f, 0.f, 0.f, 0.f);
            ((float4*)(outf + (size_t)node * FEAT + c * 8))[0] = z;
            ((float4*)(outf + (size_t)node * FEAT + c * 8))[1] = z;
        }
        if (ox && g == 0) {
            f16x8 z = {};
            *(f16x8*)(ox + (size_t)node * FEAT + c * 8) = z;
        }
        return;
    }

    const _Float16 NEGINF = (_Float16)(-65504.0f);
    f16x8 m0, m1, m2, m3;
#pragma unroll
    for (int i = 0; i < 8; ++i) { m0[i] = NEGINF; m1[i] = NEGINF; m2[i] = NEGINF; m3[i] = NEGINF; }

    for (int base = beg; base < end; base += 64) {
        int n = end - base;
        if (n > 64) n = 64;
        int nm1 = n - 1;
        int li = (lane < n) ? lane : nm1;
        int myidx = esrc[base + li];                // one coalesced load
        for (int j = 0; j < n; j += 16) {           // 16 edges per group
            bool b1 = (j + 4) < n, b2 = (j + 8) < n, b3 = (j + 12) < n;  // wave-uniform
            int s0 = j + g;       if (s0 > nm1) s0 = nm1;
            f16x8 v0 = *(const f16x8*)(t16 + (size_t)__shfl(myidx, s0) * FEAT + c * 8);
            f16x8 v1, v2, v3;
            if (b1) {
                int s1 = j + 4 + g;  if (s1 > nm1) s1 = nm1;
                v1 = *(const f16x8*)(t16 + (size_t)__shfl(myidx, s1) * FEAT + c * 8);
            }
            if (b2) {
                int s2 = j + 8 + g;  if (s2 > nm1) s2 = nm1;
                v2 = *(const f16x8*)(t16 + (size_t)__shfl(myidx, s2) * FEAT + c * 8);
            }
            if (b3) {
                int s3 = j + 12 + g; if (s3 > nm1) s3 = nm1;
                v3 = *(const f16x8*)(t16 + (size_t)__shfl(myidx, s3) * FEAT + c * 8);
            }
            m0 = vmax8(m0, v0);
            if (b1) m1 = vmax8(m1, v1);
            if (b2) m2 = vmax8(m2, v2);
            if (b3) m3 = vmax8(m3, v3);
        }
    }

    f16x8 m = vmax8(vmax8(m0, m1), vmax8(m2, m3));

    // combine the 4 edge slots (butterfly over lane bits 4 and 5)
    m = vmax8(m, shflxor8(m, 16));
    m = vmax8(m, shflxor8(m, 32));

    // epilogue on slot-0 lanes (16 lanes x 8 features = full row)
    if (g == 0) {
        f16x8 qi = *(const f16x8*)(q16 + (size_t)node * FEAT + c * 8);
        float o[8];
#pragma unroll
        for (int i = 0; i < 8; ++i)
            o[i] = fmaxf((float)m[i] + (float)qi[i], 0.f);

        if (outf) {
            float4 o0 = make_float4(o[0], o[1], o[2], o[3]);
            float4 o1 = make_float4(o[4], o[5], o[6], o[7]);
            ((float4*)(outf + (size_t)node * FEAT + c * 8))[0] = o0;
            ((float4*)(outf + (size_t)node * FEAT + c * 8))[1] = o1;
        }
        if (ox) {
            f16x8 oh;
#pragma unroll
            for (int i = 0; i < 8; ++i) oh[i] = (_Float16)o[i];
            *(f16x8*)(ox + (size_t)node * FEAT + c * 8) = oh;
        }
    }
}

// ---------------------------------------------------------------------------

extern "C" void kernel_launch(void* const* d_in, const int* in_sizes, int n_in,
                              void* d_out, int out_size, void* d_ws, size_t ws_size,
                              hipStream_t stream) {
    const float* feats   = (const float*)d_in[0];
    const int*   src     = (const int*)d_in[1];
    const int*   dst     = (const int*)d_in[2];
    const float* theta_w = (const float*)d_in[3];
    const float* theta_b = (const float*)d_in[4];
    const float* phi_w   = (const float*)d_in[5];
    const float* phi_b   = (const float*)d_in[6];

    const int N = in_sizes[0] / FEAT;
    const int E = in_sizes[1];
    const int L = in_sizes[3] / (FEAT * FEAT);

    char* ws = (char*)d_ws;
    size_t off = 0;
    auto alloc = [&](size_t bytes) -> void* {
        void* ptr = ws + off;
        off = (off + bytes + 255) & ~(size_t)255;
        return ptr;
    };
    _Float16* t16 = (_Float16*)alloc((size_t)N * FEAT * 2);
    _Float16* q16 = (_Float16*)alloc((size_t)N * FEAT * 2);
    _Float16* x16 = (_Float16*)alloc((size_t)N * FEAT * 2);
    _Float16* wt16 = (_Float16*)alloc((size_t)L * FEAT * FEAT * 2);
    _Float16* wp16 = (_Float16*)alloc((size_t)L * FEAT * FEAT * 2);
    float* bsum_b = (float*)alloc((size_t)L * FEAT * sizeof(float));
    int* deg     = (int*)alloc((size_t)N * sizeof(int));
    int* fill    = (int*)alloc((size_t)N * sizeof(int));
    int* row_ptr = (int*)alloc((size_t)(N + 1) * sizeof(int));
    int* esrc    = (int*)alloc((size_t)E * sizeof(int));
    int* bsum    = (int*)alloc(2048 * sizeof(int));
    int* boff    = (int*)alloc(2048 * sizeof(int));
    (void)ws_size;

    hipMemsetAsync(deg, 0, (size_t)N * sizeof(int), stream);
    hipMemsetAsync(fill, 0, (size_t)N * sizeof(int), stream);

    int eb = (E + 255) / 256;
    int nb = (N + 1023) >> 10;
    hist_kernel<<<eb, 256, 0, stream>>>(dst, deg, E);
    scan1_kernel<<<nb, 1024, 0, stream>>>(deg, row_ptr, bsum, N);
    scan2_kernel<<<1, 1024, 0, stream>>>(bsum, boff, row_ptr, nb, N, E);
    scan3_kernel<<<(N + 255) / 256, 256, 0, stream>>>(row_ptr, boff, N);

    int wn = L * FEAT * FEAT;
    wcvt_kernel<<<(wn + 255) / 256, 256, 0, stream>>>(
        theta_w, phi_w, theta_b, phi_b, wt16, wp16, bsum_b, wn, L * FEAT);
    int xn4 = N * FEAT / 4;
    xcvt_kernel<<<(xn4 + 255) / 256, 256, 0, stream>>>(feats, x16, xn4);

    int gb = (N + 127) / 128;
    for (int l = 0; l < L; ++l) {
        if (l == 0) {
            fused0_kernel<<<gb + eb, 256, 0, stream>>>(
                x16, wt16, wp16, bsum_b, t16, q16, N, gb,
                src, dst, row_ptr, fill, esrc, E);
        } else {
            mfma_gemm_kernel<<<gb, 256, 0, stream>>>(
                x16,
                wt16 + (size_t)l * FEAT * FEAT,
                wp16 + (size_t)l * FEAT * FEAT,
                bsum_b + (size_t)l * FEAT,
                t16, q16, N);
        }

        bool last = (l == L - 1);
        agg_kernel<<<(N + 3) / 4, 256, 0, stream>>>(
            t16, q16,
            row_ptr, esrc,
            last ? (float*)d_out : nullptr,
            last ? nullptr : x16,   // in-place: x16 fully consumed before agg runs
            N);
    }
}